// Round 1
// 3105.829 us; speedup vs baseline: 4.7060x; 4.7060x over previous
//
#include <hip/hip_runtime.h>

// GAT encoder, B=8, N=1024, D=768, H=4. adj int32; float tensors bf16 OR f32,
// runtime-detected (flag in ws). Outputs: yy [B,N,D] then node_scores [B,N].
//
// MFMA ROUND: all GEMMs on v_mfma_f32_16x16x32_f16 (fp16 internal dtype —
// 3 more mantissa bits than the previous bf16 intermediates at the same rate).
// Every GEMM's B operand is pre-transposed (BT[n][k]) so BOTH fragments read
// contiguous-K via swizzled ds_read_b128. Wh1/Wh2 are written transposed at
// the producing GEMM's epilogue (packed f16x4 stores, rows consecutive/lane).
//
// ws (peak 6,824,192 B, same as previous round):
//   f1 f32[1024] @0, f2 @4096, flag @8192,
//   Wh1T f16[768,1024] @8448, Wh2T @1581312, att f16[1024,1024] @3154176,
//   WT f16[768,768] ALIASES att (live only T1->G1 and T2->G3, att only A1->G2/A2->G4),
//   hout f16[1024,768] @5251328 (end 6,824,192).
// Per b: { per h: T1 WT=Wh[h]^T; G1 Wh1T=(X W)^T; F1; A1->att;
//          G2 hout=elu(att@Wh1); T2 WT=Wo[h]^T; G3 Wh2T (+)= (hout Wo)^T }
//        F2; A2; G4 yy[b]=elu(att2@Wh2)+X[b]; then cls.

typedef unsigned short ushortT;
typedef _Float16 f16;
typedef __attribute__((ext_vector_type(8))) _Float16 f16x8;
typedef __attribute__((ext_vector_type(4))) _Float16 f16x4;
typedef __attribute__((ext_vector_type(4))) float f32x4;
typedef __attribute__((ext_vector_type(8))) unsigned short u16x8;

#define ALPHA 0.2f

__device__ __forceinline__ float b2f(ushortT u) {
  union { unsigned int i; float f; } c; c.i = ((unsigned int)u) << 16; return c.f;
}
__device__ __forceinline__ ushortT f2b(float f) {
  union { float f; unsigned int u; } c; c.f = f;
  unsigned int u = c.u;
  u += 0x7FFFu + ((u >> 16) & 1u);   // RNE
  return (ushortT)(u >> 16);
}

// ---- dtype detector: low 16-bit halves of f32 words are mantissa noise -------
__global__ void detect_dtype(const ushortT* __restrict__ X, int* __restrict__ flag) {
  __shared__ int s[256];
  int t = threadIdx.x, c = 0;
  for (int i = t; i < 16384; i += 256) {
    int e = (X[2 * i] >> 7) & 0xFF;
    if (e > 140 || e < 100) c++;     // genuine bf16 N(0,1): essentially never
  }
  s[t] = c; __syncthreads();
  for (int o = 128; o > 0; o >>= 1) { if (t < o) s[t] += s[t + o]; __syncthreads(); }
  if (t == 0) *flag = (s[0] > 1000) ? 1 : 0;   // 1 -> inputs are f32
}

// ---- 768x768 weight transpose: WT[c][r] = W[wOff + r*768 + c], f16 out -------
__global__ __launch_bounds__(256) void transpose_w(
    const void* __restrict__ W, f16* __restrict__ WT, long wOff,
    const int* __restrict__ rflag) {
  __shared__ float tile[32][33];
  int flg = *rflag;
  int tx = threadIdx.x & 31, ty = threadIdx.x >> 5;
  int c0 = blockIdx.x * 32, r0 = blockIdx.y * 32;
  const float* Wf = (const float*)W; const ushortT* Wu = (const ushortT*)W;
#pragma unroll
  for (int i = 0; i < 4; i++) {
    int r = r0 + ty + i * 8;
    long gi = wOff + (long)r * 768 + c0 + tx;
    tile[ty + i * 8][tx] = flg ? Wf[gi] : b2f(Wu[gi]);
  }
  __syncthreads();
#pragma unroll
  for (int i = 0; i < 4; i++) {
    int c = c0 + ty + i * 8;
    WT[(long)c * 768 + r0 + tx] = (f16)tile[tx][ty + i * 8];
  }
}

// ---- MFMA GEMM: C[1024,768] = A[1024,K] @ B[K,768], B given transposed ------
// BT is [768][K] f16 (row stride K). A dtype: aRaw=0 -> f16; aRaw=1 -> flag
// dispatch (f32 or bf16), converted to f16 at stage time.
// MODE 1: elu, f16, normal layout (hout). MODE 2: elu + residual(raw), store
// flag dtype at cOff (final yy). MODE 3: f16 accumulate, TRANSPOSED store
// (Wh2T). MODE 4: f16 plain TRANSPOSED store (Wh1T).
// Block 256 = 4 waves (2x2 of 32x32), tile BM=64 BN=64 BK=64, grid (12,16).
// LDS rows are 128 B; 16 B-chunk index XOR-swizzled with (row&7) so staging
// ds_write_b128 and fragment ds_read_b128 are both conflict-free (G4).
template <int MODE>
__global__ __launch_bounds__(256) void mgemm(
    const void* __restrict__ Ab, const f16* __restrict__ BT,
    void* __restrict__ Cb, const void* __restrict__ Rb,
    int K, int lda, int aRaw,
    long aOff, long cOff, long rOff, int accum,
    const int* __restrict__ rflag) {
  __shared__ __align__(16) f16 As[64 * 64];
  __shared__ __align__(16) f16 Bs[64 * 64];
  int t = threadIdx.x;
  int n0 = blockIdx.x * 64, m0 = blockIdx.y * 64;
  int flg = *rflag;
  int aTy = aRaw ? (flg ? 2 : 1) : 0;   // 0 f16, 1 bf16, 2 f32

  // staging: thread t owns tile row tq, 16-element k-group cq (2 chunks of 8)
  int tq = t >> 2, cq = t & 3;
  long aBase = aOff + (long)(m0 + tq) * lda + cq * 16;
  long bBase = (long)(n0 + tq) * (long)K + cq * 16;
  int st0 = tq * 64 + (((2 * cq)     ^ (tq & 7)) * 8);
  int st1 = tq * 64 + (((2 * cq + 1) ^ (tq & 7)) * 8);

  const f16*     Ah = (const f16*)Ab;
  const ushortT* Au = (const ushortT*)Ab;
  const float*   Af = (const float*)Ab;

  f16x8 ra0, ra1, rb0, rb1;   // prefetch regs

  auto loadA = [&](int kt) {
    long g = aBase + (long)kt * 64;
    if (aTy == 0) {
      ra0 = *(const f16x8*)(Ah + g);
      ra1 = *(const f16x8*)(Ah + g + 8);
    } else if (aTy == 1) {
      u16x8 v0 = *(const u16x8*)(Au + g);
      u16x8 v1 = *(const u16x8*)(Au + g + 8);
#pragma unroll
      for (int j = 0; j < 8; j++) { ra0[j] = (f16)b2f(v0[j]); ra1[j] = (f16)b2f(v1[j]); }
    } else {
      f32x4 v0 = *(const f32x4*)(Af + g);
      f32x4 v1 = *(const f32x4*)(Af + g + 4);
      f32x4 v2 = *(const f32x4*)(Af + g + 8);
      f32x4 v3 = *(const f32x4*)(Af + g + 12);
#pragma unroll
      for (int j = 0; j < 4; j++) {
        ra0[j] = (f16)v0[j]; ra0[4 + j] = (f16)v1[j];
        ra1[j] = (f16)v2[j]; ra1[4 + j] = (f16)v3[j];
      }
    }
  };
  auto loadB = [&](int kt) {
    long g = bBase + (long)kt * 64;
    rb0 = *(const f16x8*)(BT + g);
    rb1 = *(const f16x8*)(BT + g + 8);
  };

  // compute-side lane geometry
  int lane = t & 63, wid = t >> 6;
  int wr = wid >> 1, wc = wid & 1;            // 2x2 waves of 32x32
  int lr = lane & 15, lg = lane >> 4, l7 = lane & 7;
  int aRow0 = (wr * 32 + lr) * 64, aRow1 = aRow0 + 16 * 64;
  int bRow0 = (wc * 32 + lr) * 64, bRow1 = bRow0 + 16 * 64;

  f32x4 acc[2][2];
#pragma unroll
  for (int i = 0; i < 2; i++)
#pragma unroll
    for (int j = 0; j < 2; j++) acc[i][j] = (f32x4){0.f, 0.f, 0.f, 0.f};

  int KT = K >> 6;
  loadA(0); loadB(0);
  for (int kt = 0; kt < KT; ++kt) {
    __syncthreads();                       // previous tile's readers done
    *(f16x8*)(As + st0) = ra0;  *(f16x8*)(As + st1) = ra1;
    *(f16x8*)(Bs + st0) = rb0;  *(f16x8*)(Bs + st1) = rb1;
    __syncthreads();
    if (kt + 1 < KT) { loadA(kt + 1); loadB(kt + 1); }  // overlap with MFMAs
#pragma unroll
    for (int kk = 0; kk < 2; kk++) {
      int ch = ((kk * 4 + lg) ^ l7) * 8;   // swizzled 16B chunk
      f16x8 a0 = *(const f16x8*)(As + aRow0 + ch);
      f16x8 a1 = *(const f16x8*)(As + aRow1 + ch);
      f16x8 b0 = *(const f16x8*)(Bs + bRow0 + ch);
      f16x8 b1 = *(const f16x8*)(Bs + bRow1 + ch);
      acc[0][0] = __builtin_amdgcn_mfma_f32_16x16x32_f16(a0, b0, acc[0][0], 0, 0, 0);
      acc[0][1] = __builtin_amdgcn_mfma_f32_16x16x32_f16(a0, b1, acc[0][1], 0, 0, 0);
      acc[1][0] = __builtin_amdgcn_mfma_f32_16x16x32_f16(a1, b0, acc[1][0], 0, 0, 0);
      acc[1][1] = __builtin_amdgcn_mfma_f32_16x16x32_f16(a1, b1, acc[1][1], 0, 0, 0);
    }
  }

  // epilogue: C frag mapping col = lane&15, row = 4*(lane>>4)+reg  [m89]
  int rowb_base = m0 + wr * 32 + 4 * lg;
  int col_base  = n0 + wc * 32 + lr;
#pragma unroll
  for (int fm = 0; fm < 2; fm++) {
#pragma unroll
    for (int fn = 0; fn < 2; fn++) {
      int rowb = rowb_base + fm * 16;
      int col  = col_base + fn * 16;
      f32x4 v = acc[fm][fn];
      if (MODE == 4) {                       // transposed plain store (Wh1T)
        f16x4 pk;
#pragma unroll
        for (int r = 0; r < 4; r++) pk[r] = (f16)v[r];
        *(f16x4*)((f16*)Cb + (long)col * 1024 + rowb) = pk;
      } else if (MODE == 3) {                // transposed accumulate (Wh2T)
        f16* Cc = (f16*)Cb;
        long idx = (long)col * 1024 + rowb;
        f16x4 pk;
        if (accum) {
          f16x4 old = *(const f16x4*)(Cc + idx);
#pragma unroll
          for (int r = 0; r < 4; r++) pk[r] = (f16)((float)old[r] + v[r]);
        } else {
#pragma unroll
          for (int r = 0; r < 4; r++) pk[r] = (f16)v[r];
        }
        *(f16x4*)(Cc + idx) = pk;
      } else {
#pragma unroll
        for (int r = 0; r < 4; r++) {
          int row = rowb + r;
          float x = v[r];
          x = x > 0.f ? x : expm1f(x);       // elu (MODE 1 and 2)
          long ci = cOff + (long)row * 768 + col;
          if (MODE == 2) {
            long ri = rOff + (long)row * 768 + col;
            x += flg ? ((const float*)Rb)[ri] : b2f(((const ushortT*)Rb)[ri]);
            if (flg) ((float*)Cb)[ci] = x;
            else     ((ushortT*)Cb)[ci] = f2b(x);
          } else {
            ((f16*)Cb)[ci] = (f16)x;
          }
        }
      }
    }
  }
}

// ---- f1/f2 dots on TRANSPOSED Wh (WhT [768][1024] f16): coalesced on nodes --
__global__ __launch_bounds__(256) void fdotT_kernel(
    const f16* __restrict__ WhT, const void* __restrict__ avec, long aOff,
    float* __restrict__ f1, float* __restrict__ f2, const int* __restrict__ rflag) {
  __shared__ float s1m[8][32], s2m[8][32];
  int t = threadIdx.x, n = t & 31, fl = t >> 5;
  int node = blockIdx.x * 32 + n;
  int flg = *rflag;
  const float* af = (const float*)avec; const ushortT* au = (const ushortT*)avec;
  float s1 = 0.f, s2 = 0.f;
  for (int f = fl; f < 768; f += 8) {
    float wv = (float)WhT[(long)f * 1024 + node];
    float a1 = flg ? af[aOff + f]       : b2f(au[aOff + f]);
    float a2 = flg ? af[aOff + 768 + f] : b2f(au[aOff + 768 + f]);
    s1 += wv * a1; s2 += wv * a2;
  }
  s1m[fl][n] = s1; s2m[fl][n] = s2;
  __syncthreads();
  if (t < 32) {
    float r1 = 0.f, r2 = 0.f;
#pragma unroll
    for (int j = 0; j < 8; j++) { r1 += s1m[j][t]; r2 += s2m[j][t]; }
    f1[blockIdx.x * 32 + t] = r1;
    f2[blockIdx.x * 32 + t] = r2;
  }
}

// ---- masked row softmax over 1024 cols; one block per row i; f16 out ---------
__global__ __launch_bounds__(256) void attn_kernel(
    const float* __restrict__ f1, const float* __restrict__ f2,
    const int* __restrict__ adj, f16* __restrict__ att) {
  __shared__ float sred[8];
  int i = blockIdx.x;
  const int* arow = adj + (size_t)i * 1024;
  float f1i = f1[i];
  f16* orow = att + (size_t)i * 1024;
  int t = threadIdx.x, lane = t & 63, wid = t >> 6;

  float e[4];
  int msk[4];
  float mx = -1e38f;
#pragma unroll
  for (int c = 0; c < 4; c++) {
    int j = t + c * 256;
    float ev = f1i + f2[j];
    ev = ev > 0.f ? ev : ALPHA * ev;
    e[c] = ev;
    msk[c] = arow[j] > 0;
    if (msk[c]) mx = fmaxf(mx, ev);
  }
#pragma unroll
  for (int o = 32; o > 0; o >>= 1) mx = fmaxf(mx, __shfl_down(mx, o));
  if (lane == 0) sred[wid] = mx;
  __syncthreads();
  float bmx = fmaxf(fmaxf(sred[0], sred[1]), fmaxf(sred[2], sred[3]));
  bool none = bmx < -1e37f;   // all-masked row -> reference softmax is uniform

  float p[4];
  float sum = 0.f;
#pragma unroll
  for (int c = 0; c < 4; c++) {
    p[c] = none ? 1.f : (msk[c] ? expf(e[c] - bmx) : 0.f);
    sum += p[c];
  }
#pragma unroll
  for (int o = 32; o > 0; o >>= 1) sum += __shfl_down(sum, o);
  if (lane == 0) sred[4 + wid] = sum;
  __syncthreads();
  float inv = 1.f / (sred[4] + sred[5] + sred[6] + sred[7]);
#pragma unroll
  for (int c = 0; c < 4; c++) orow[t + c * 256] = (f16)(p[c] * inv);
}

// ---- classifier: scores[row] = sigmoid(yy[row]@w + b) * mask[row] ------------
__global__ __launch_bounds__(256) void cls_kernel(
    void* __restrict__ outbase, const void* __restrict__ w,
    const void* __restrict__ bc, const void* __restrict__ mask,
    const int* __restrict__ rflag) {
  int t = threadIdx.x, lane = t & 63, wv = t >> 6;
  long row = (long)blockIdx.x * 4 + wv;    // 0..8191
  int f32 = *rflag;
  const float* yf = (const float*)outbase; const ushortT* yu = (const ushortT*)outbase;
  const float* wf = (const float*)w;       const ushortT* wu = (const ushortT*)w;
  float s = 0.f;
  for (int d = lane; d < 768; d += 64) {
    float yv = f32 ? yf[row * 768 + d] : b2f(yu[row * 768 + d]);
    float wvv = f32 ? wf[d] : b2f(wu[d]);
    s += yv * wvv;
  }
#pragma unroll
  for (int o = 32; o > 0; o >>= 1) s += __shfl_down(s, o);
  if (lane == 0) {
    float bb = f32 ? ((const float*)bc)[0] : b2f(((const ushortT*)bc)[0]);
    float mk = f32 ? ((const float*)mask)[row] : b2f(((const ushortT*)mask)[row]);
    float sig = 1.f / (1.f + expf(-(s + bb)));
    long oi = 6291456L + row;
    if (f32) ((float*)outbase)[oi] = sig * mk;
    else ((ushortT*)outbase)[oi] = f2b(sig * mk);
  }
}

extern "C" void kernel_launch(void* const* d_in, const int* in_sizes, int n_in,
                              void* d_out, int out_size, void* d_ws, size_t ws_size,
                              hipStream_t stream) {
  (void)in_sizes; (void)n_in; (void)out_size; (void)ws_size;

  const void* X    = d_in[0];               // [8,1024,768]
  const int*  adj  = (const int*)d_in[1];   // [8,1024,1024]
  const void* maskN= d_in[2];               // [8,1024]
  const void* Wh   = d_in[3];               // [4,768,768]
  const void* aH   = d_in[4];               // [4,1536]
  const void* Wo   = d_in[5];               // [3072,768]
  const void* aO   = d_in[6];               // [1536]
  const void* wcls = d_in[7];               // [768]
  const void* bcls = d_in[8];               // [1]

  char* ws = (char*)d_ws;
  float* f1   = (float*)(ws + 0);           // [1024]
  float* f2   = (float*)(ws + 4096);        // [1024]
  int*   flag = (int*)(ws + 8192);
  f16* Wh1T = (f16*)(ws + 8448);            // [768,1024] f16
  f16* Wh2T = (f16*)(ws + 1581312);         // [768,1024] f16
  f16* attb = (f16*)(ws + 3154176);         // [1024,1024] f16
  f16* WT   = (f16*)(ws + 3154176);         // [768,768] f16, ALIASES attb
  f16* hout = (f16*)(ws + 5251328);         // [1024,768] f16; end 6,824,192

  detect_dtype<<<1, 256, 0, stream>>>((const ushortT*)X, flag);

  dim3 gg(12, 16);     // N tiles x M tiles (64x64)
  dim3 tg(24, 24);     // 32x32 transpose tiles
  for (int b = 0; b < 8; b++) {
    long xOff = (long)b * 786432;
    for (int h = 0; h < 4; h++) {
      // T1: WT = W_heads[h]^T (f16)
      transpose_w<<<tg, 256, 0, stream>>>(Wh, WT, (long)h * 589824, flag);
      // G1: Wh1T = (X[b] @ W_heads[h])^T
      mgemm<4><<<gg, 256, 0, stream>>>(X, WT, Wh1T, nullptr,
                                       768, 768, 1, xOff, 0L, 0L, 0, flag);
      // F1
      fdotT_kernel<<<32, 256, 0, stream>>>(Wh1T, aH, (long)h * 1536, f1, f2, flag);
      // A1
      attn_kernel<<<1024, 256, 0, stream>>>(f1, f2, adj + (size_t)b * 1048576, attb);
      // G2: hout = elu(att @ Wh1)
      mgemm<1><<<gg, 256, 0, stream>>>(attb, Wh1T, hout, nullptr,
                                       1024, 1024, 0, 0L, 0L, 0L, 0, flag);
      // T2: WT = W_out[h*768:(h+1)*768, :]^T  (att consumed by G2 -> safe)
      transpose_w<<<tg, 256, 0, stream>>>(Wo, WT, (long)h * 589824, flag);
      // G3: Wh2T (+)= (hout @ Wo_slice)^T
      mgemm<3><<<gg, 256, 0, stream>>>(hout, WT, Wh2T, nullptr,
                                       768, 768, 0, 0L, 0L, 0L, h > 0 ? 1 : 0, flag);
    }
    // F2 / A2 on layer-2 features
    fdotT_kernel<<<32, 256, 0, stream>>>(Wh2T, aO, 0L, f1, f2, flag);
    attn_kernel<<<1024, 256, 0, stream>>>(f1, f2, adj + (size_t)b * 1048576, attb);
    // G4: yy[b] = elu(att2 @ Wh2) + X[b]  -> d_out (flag dtype)
    mgemm<2><<<gg, 256, 0, stream>>>(attb, Wh2T, d_out, X,
                                     1024, 1024, 0, 0L, xOff, xOff, 0, flag);
  }

  cls_kernel<<<2048, 256, 0, stream>>>(d_out, wcls, bcls, maskN, flag);
}